// Round 7
// baseline (607.338 us; speedup 1.0000x reference)
//
#include <hip/hip_runtime.h>
#include <hip/hip_bf16.h>
#include <stdint.h>

// HMPNN layer: two NNConv(sum-agg)+sigmoid, concat, Linear(32,32), sigmoid.
// R3: z-outer-product: msg[e,:] = z[e,:] @ W' (k=288), MFMA 16x16x32 bf16.
// R7: scattered fp32 atomics proven structural wall (~1.45 TB/s, WRITE==atomic
//     volume regardless of scope — R3/R4/R6). Replace with dst-binned 2-phase:
//     hist -> scan (batch layout, 16-padded per node) -> scatter (src,eid) ->
//     per-batch MFMA + in-wave column sum -> ONE plain 64B store per batch
//     (bpart) -> finalize sums each node's contiguous batch partials.
//     Zero fp32 scatter-atomics anywhere.

#define NN 50000
#define EE 800000
#define SLOT 1600000   // padded slot capacity per metastep (= 16 * BN)
#define BN   100000    // batches/metastep bound: sum max(1,ceil(d/16)) <= 50K + 800K/16

typedef __attribute__((ext_vector_type(8))) short short8;
typedef __attribute__((ext_vector_type(4))) float f32x4;

union U8 { short8 v; unsigned int u[4]; };

__device__ __forceinline__ unsigned short f2bf_rne(float f) {
    union { float fl; unsigned int i; } v; v.fl = f;
    unsigned int x = v.i;
    x += 0x7FFFu + ((x >> 16) & 1u);
    return (unsigned short)(x >> 16);
}

__device__ __forceinline__ unsigned int pack2bf(float a, float b) {
    __hip_bfloat162 h = __float22bfloat162_rn(float2{a, b}); // x=low, y=high
    union { __hip_bfloat162 h2; unsigned int u; } c; c.h2 = h;
    return c.u;
}

// Wfrag[t][lane][j] = bf16( W'[32t + (lane>>4)*8 + j][lane&15] ), t=0..8.
__global__ void prep_w(const float* __restrict__ w_msg_a, const float* __restrict__ b_msg_a,
                       unsigned short* __restrict__ wf_a,
                       const float* __restrict__ w_msg_b, const float* __restrict__ b_msg_b,
                       unsigned short* __restrict__ wf_b) {
    const float* w_msg = blockIdx.x ? w_msg_b : w_msg_a;
    const float* b_msg = blockIdx.x ? b_msg_b : b_msg_a;
    unsigned short* wfrag = blockIdx.x ? wf_b : wf_a;
    for (int idx = threadIdx.x; idx < 9 * 64 * 8; idx += 256) {
        int j = idx & 7;
        int lane = (idx >> 3) & 63;
        int t = idx >> 9;
        int k = 32 * t + (lane >> 4) * 8 + j;
        int n = lane & 15;
        int f = k >> 4, i = k & 15;
        float v = (f < 16) ? w_msg[f * 256 + i * 16 + n]
                           : (f == 16 ? b_msg[i * 16 + n] : 0.f);
        wfrag[idx] = f2bf_rne(v);
    }
}

// Per-dst degree histogram, both metasteps in one dispatch (idx >= EE -> b).
__global__ __launch_bounds__(256) void hist(const int* __restrict__ ei_a,
                                            const int* __restrict__ ei_b,
                                            unsigned int* __restrict__ cnt) {
    int idx = blockIdx.x * 256 + threadIdx.x;   // exact grid: 2*EE/256
    int ms = idx >= EE;
    int el = idx - ms * EE;
    const int* ei = ms ? ei_b : ei_a;
    atomicAdd(&cnt[ms * NN + ei[EE + el]], 1u);
}

// One block per metastep. Exclusive scan of per-node batch counts
// bc[n] = max(1, ceil(cnt/16)); emits: bstart[n] (batch prefix), cursor[n]
// (= bstart*16, scatter slot cursor), binfo[b] = (n<<16)|k for each batch.
__global__ __launch_bounds__(1024) void scan_fill(const unsigned int* __restrict__ cnt,
                                                  unsigned int* __restrict__ cursor,
                                                  unsigned int* __restrict__ bstart,
                                                  unsigned int* __restrict__ binfo) {
    int ms = blockIdx.x;
    const unsigned int* c = cnt + ms * NN;
    unsigned int* cur = cursor + ms * NN;
    unsigned int* bs = bstart + ms * (NN + 1);
    unsigned int* bi = binfo + ms * BN;
    int t = threadIdx.x;
    const int C = 49;                 // 1024*49 = 50176 >= NN
    int s0 = t * C, s1 = s0 + C;
    if (s1 > NN) s1 = NN;
    if (s0 > NN) s0 = NN;

    unsigned int acc = 0;
    for (int n = s0; n < s1; ++n)
        acc += max(1u, (c[n] + 15u) >> 4);

    __shared__ unsigned int sA[1024], sB[1024];
    sA[t] = acc;
    __syncthreads();
    unsigned int* src = sA; unsigned int* dst = sB;
    for (int d = 1; d < 1024; d <<= 1) {
        unsigned int v = src[t] + ((t >= d) ? src[t - d] : 0u);
        dst[t] = v;
        __syncthreads();
        unsigned int* tmp = src; src = dst; dst = tmp;
    }
    unsigned int b = (t == 0) ? 0u : src[t - 1];   // exclusive prefix

    for (int n = s0; n < s1; ++n) {
        unsigned int bc = max(1u, (c[n] + 15u) >> 4);
        bs[n] = b;
        cur[n] = b * 16u;
        for (unsigned int k = 0; k < bc; ++k)
            bi[b + k] = ((unsigned int)n << 16) | k;
        b += bc;
    }
    if (s1 == NN && s0 < NN) bs[NN] = b;           // total batches
}

// Scatter edges into 16-padded per-dst slots.
__global__ __launch_bounds__(256) void scatter(const int* __restrict__ ei_a,
                                               const int* __restrict__ ei_b,
                                               unsigned int* __restrict__ cursor,
                                               int* __restrict__ srcid,
                                               int* __restrict__ eid) {
    int idx = blockIdx.x * 256 + threadIdx.x;
    int ms = idx >= EE;
    int el = idx - ms * EE;
    const int* ei = ms ? ei_b : ei_a;
    int d = ei[EE + el];
    unsigned int pos = atomicAdd(&cursor[ms * NN + d], 1u);
    srcid[ms * SLOT + pos] = ei[el];
    eid[ms * SLOT + pos]   = el;
}

// One batch (= 16 same-dst edge slots) per wave-iteration; R3's A-frag build
// and 9-step MFMA; column-sum across quads (2 shfl_xor) -> bpart[batch][16]
// plain 64B store. Pad lanes masked via m < cnt[n]-16k. Fused metasteps.
__global__ __launch_bounds__(256) void edge_mfma_s(
    const float* __restrict__ ea_a, const float* __restrict__ x_a,
    const unsigned short* __restrict__ wf_a,
    const float* __restrict__ ea_b, const float* __restrict__ x_b,
    const unsigned short* __restrict__ wf_b,
    const unsigned int* __restrict__ cnt, const unsigned int* __restrict__ bstart,
    const unsigned int* __restrict__ binfo,
    const int* __restrict__ srcid, const int* __restrict__ eid,
    float* __restrict__ bpart)
{
    int ms = blockIdx.x & 1;
    const float* attr = ms ? ea_b : ea_a;
    const float* x    = ms ? x_b : x_a;
    const unsigned short* wfrag = ms ? wf_b : wf_a;
    const unsigned int* c  = cnt + ms * NN;
    const unsigned int* bi = binfo + ms * BN;
    const int* sid  = srcid + ms * SLOT;
    const int* eidm = eid + ms * SLOT;
    float* bp = bpart + (size_t)ms * BN * 16;
    int nb = (int)bstart[ms * (NN + 1) + NN];

    int lane = threadIdx.x & 63;
    int m = lane & 15, quad = lane >> 4;
    int q2 = quad >> 1, qb = quad & 1;
    int wave = ((blockIdx.x >> 1) * 256 + (int)threadIdx.x) >> 6;
    int nwaves = (gridDim.x >> 1) * 4;

    short8 bfr[9];
    #pragma unroll
    for (int t = 0; t < 9; ++t)
        bfr[t] = ((const short8*)wfrag)[t * 64 + lane];

    for (int g = wave; g < nb; g += nwaves) {
        unsigned int info = bi[g];
        int n = (int)(info >> 16);
        int k = (int)(info & 0xFFFFu);
        int vc = (int)c[n] - k * 16;        // valid lanes in this batch
        bool ok = m < vc;
        int slot = g * 16 + m;
        int ev = eidm[slot];
        int sv = sid[slot];
        int ea = ok ? ev : 0;               // clamp BEFORE deref (pad = garbage)
        int sa = ok ? sv : 0;

        const f32x4* xr = (const f32x4*)(x + (size_t)sa * 16);
        f32x4 x0 = xr[qb * 2];
        f32x4 x1 = xr[qb * 2 + 1];
        float xh[8] = {x0.x, x0.y, x0.z, x0.w, x1.x, x1.y, x1.z, x1.w};
        #pragma unroll
        for (int j = 0; j < 8; ++j) xh[j] = ok ? xh[j] : 0.f;  // bias row mask

        const float* ar = attr + (size_t)ea * 16;
        float ah[8];
        #pragma unroll
        for (int t = 0; t < 8; ++t) {
            float av = ar[2 * t + q2];
            ah[t] = ok ? av : 0.f;
        }

        f32x4 acc = {0.f, 0.f, 0.f, 0.f};
        #pragma unroll
        for (int t = 0; t < 8; ++t) {
            U8 a;
            #pragma unroll
            for (int jj = 0; jj < 4; ++jj)
                a.u[jj] = pack2bf(ah[t] * xh[2 * jj], ah[t] * xh[2 * jj + 1]);
            acc = __builtin_amdgcn_mfma_f32_16x16x32_bf16(a.v, bfr[t], acc, 0, 0, 0);
        }
        U8 a8;
        #pragma unroll
        for (int jj = 0; jj < 4; ++jj)
            a8.u[jj] = (q2 == 0) ? pack2bf(xh[2 * jj], xh[2 * jj + 1]) : 0u;
        acc = __builtin_amdgcn_mfma_f32_16x16x32_bf16(a8.v, bfr[8], acc, 0, 0, 0);

        // column sum over the 16 edge-rows: 4 regs + cross-quad butterfly
        float s = acc[0] + acc[1] + acc[2] + acc[3];
        s += __shfl_xor(s, 16);
        s += __shfl_xor(s, 32);
        if (lane < 16) bp[(size_t)g * 16 + lane] = s;   // plain 64B store/batch
    }
}

// out[n,d] = sigmoid( h @ w_lin + b_lin ),
// h = sigmoid( sum_batches bpart + x@root + bias )
__global__ __launch_bounds__(256) void finalize(
    const float* __restrict__ xind,
    const unsigned int* __restrict__ bstart, const float* __restrict__ bpart,
    const float* __restrict__ root_a, const float* __restrict__ bias_a,
    const float* __restrict__ root_b, const float* __restrict__ bias_b,
    const float* __restrict__ w_lin, const float* __restrict__ b_lin,
    float* __restrict__ out)
{
    int tid = threadIdx.x;
    int n = blockIdx.x * 8 + (tid >> 5);
    if (n >= NN) return;
    int d = tid & 31;
    int lane = tid & 63;
    int gb32 = lane & ~31;

    float xv = xind[n * 16 + (d & 15)];

    int j = d & 15;
    const float* root = (d < 16) ? root_a : root_b;
    const float* bias = (d < 16) ? bias_a : bias_b;
    const unsigned int* bs = bstart + ((d < 16) ? 0 : (NN + 1));
    const float* bp = bpart + ((d < 16) ? 0 : (size_t)BN * 16);

    float acc = bias[j];
    unsigned int b0 = bs[n], b1 = bs[n + 1];
    for (unsigned int b = b0; b < b1; ++b)
        acc += bp[(size_t)b * 16 + j];
    #pragma unroll
    for (int i = 0; i < 16; ++i) {
        float xiv = __shfl(xv, gb32 + i);
        acc += xiv * root[i * 16 + j];
    }
    float h = 1.f / (1.f + __expf(-acc));

    float acc2 = b_lin[d];
    #pragma unroll
    for (int jj = 0; jj < 32; ++jj) {
        float hj = __shfl(h, gb32 + jj);
        acc2 += hj * w_lin[jj * 32 + d];
    }
    out[(size_t)n * 32 + d] = 1.f / (1.f + __expf(-acc2));
}

static inline size_t align512(size_t x) { return (x + 511) & ~(size_t)511; }

extern "C" void kernel_launch(void* const* d_in, const int* in_sizes, int n_in,
                              void* d_out, int out_size, void* d_ws, size_t ws_size,
                              hipStream_t stream) {
    (void)in_sizes; (void)n_in; (void)out_size; (void)ws_size;
    const float* x_indivi = (const float*)d_in[0];
    const float* x_src_a  = (const float*)d_in[1];
    const float* x_src_b  = (const float*)d_in[2];
    const int*   ei_a     = (const int*)d_in[3];
    const int*   ei_b     = (const int*)d_in[4];
    const float* ea_a     = (const float*)d_in[5];
    const float* ea_b     = (const float*)d_in[6];
    const float* w_msg_a  = (const float*)d_in[7];
    const float* b_msg_a  = (const float*)d_in[8];
    const float* root_a   = (const float*)d_in[9];
    const float* bias_a   = (const float*)d_in[10];
    const float* w_msg_b  = (const float*)d_in[11];
    const float* b_msg_b  = (const float*)d_in[12];
    const float* root_b   = (const float*)d_in[13];
    const float* bias_b   = (const float*)d_in[14];
    const float* w_lin    = (const float*)d_in[15];
    const float* b_lin    = (const float*)d_in[16];
    float* out = (float*)d_out;

    char* ws = (char*)d_ws;
    size_t off = 0;
    unsigned short* wf_a = (unsigned short*)(ws + off); off = align512(off + 9 * 64 * 8 * 2);
    unsigned short* wf_b = (unsigned short*)(ws + off); off = align512(off + 9 * 64 * 8 * 2);
    unsigned int* cnt    = (unsigned int*)(ws + off);   off = align512(off + 2 * NN * 4);
    unsigned int* cursor = (unsigned int*)(ws + off);   off = align512(off + 2 * NN * 4);
    unsigned int* bstart = (unsigned int*)(ws + off);   off = align512(off + 2 * (NN + 1) * 4);
    unsigned int* binfo  = (unsigned int*)(ws + off);   off = align512(off + 2 * (size_t)BN * 4);
    int* srcid           = (int*)(ws + off);            off = align512(off + 2 * (size_t)SLOT * 4);
    int* eid             = (int*)(ws + off);            off = align512(off + 2 * (size_t)SLOT * 4);
    float* bpart         = (float*)(ws + off);          off = align512(off + 2 * (size_t)BN * 16 * 4);
    // total ~40.6 MB (R6 used 51.2 MB OK)

    (void)hipMemsetAsync(cnt, 0, 2 * NN * 4, stream);   // only memset needed
    prep_w<<<2, 256, 0, stream>>>(w_msg_a, b_msg_a, wf_a, w_msg_b, b_msg_b, wf_b);
    hist<<<(2 * EE) / 256, 256, 0, stream>>>(ei_a, ei_b, cnt);
    scan_fill<<<2, 1024, 0, stream>>>(cnt, cursor, bstart, binfo);
    scatter<<<(2 * EE) / 256, 256, 0, stream>>>(ei_a, ei_b, cursor, srcid, eid);
    edge_mfma_s<<<4096, 256, 0, stream>>>(ea_a, x_src_a, wf_a, ea_b, x_src_b, wf_b,
                                          cnt, bstart, binfo, srcid, eid, bpart);
    finalize<<<(NN + 7) / 8, 256, 0, stream>>>(
        x_indivi, bstart, bpart, root_a, bias_a, root_b, bias_b, w_lin, b_lin, out);
}